// Round 5
// baseline (40.755 us; speedup 1.0000x reference)
//
#include <hip/hip_runtime.h>

#define IMG_H 512
#define IMG_W 512
#define NCH   24   // 8 batches * 3 channels

__device__ __forceinline__ float fexp2(float x) {
#if __has_builtin(__builtin_amdgcn_exp2f)
    return __builtin_amdgcn_exp2f(x);
#else
    float r; asm("v_exp_f32 %0, %1" : "=v"(r) : "v"(x)); return r;
#endif
}
__device__ __forceinline__ float frcp(float x) {
#if __has_builtin(__builtin_amdgcn_rcpf)
    return __builtin_amdgcn_rcpf(x);
#else
    float r; asm("v_rcp_f32 %0, %1" : "=v"(r) : "v"(x)); return r;
#endif
}

// exp(-r2/2) (double, folded at compile time)
__device__ __forceinline__ constexpr double exs(int r2) {
    return (r2 == 0) ? 1.0
         : (r2 == 1) ? 0.60653065971263342
         : (r2 == 2) ? 0.36787944117144233
         : (r2 == 4) ? 0.13533528323661270
         : (r2 == 5) ? 0.08208499862389880
         : (r2 == 8) ? 0.01831563888873418 : 0.0;
}
#define SSUM 6.16892408102888092
__device__ __forceinline__ constexpr float gkc(int r2) { return (float)(exs(r2) / SSUM); }
// 1D gaussian taps k1[d]=exp(-d^2/2), and normalized-by-SSUM variant for the row pass
__device__ __forceinline__ constexpr float k1(int d)  { return (float)exs(d * d); }
__device__ __forceinline__ constexpr float k1n(int d) { return (float)(exs(d * d) / SSUM); }
// -50/ln2 (intensity) and -0.5/ln2 (spatial, per unit r2), log2 domain
#define NEG50  -72.134752044448169f
#define LG     -0.72134752044448169f

// Interior: 2x4-pixel tiles. x0 in {4..504} (126 groups), row-pairs y0 in {2,4,..,508} (254)
#define XG_INT 126
#define YT_INT 254
#define PER_CH_T (XG_INT * YT_INT)        // 32004 tiles/channel
#define N_INT (PER_CH_T * NCH)            // 768,096 threads
// Border: 4 full rows (y=0,1,510,511)*128 groups + 508 rows * 2 edge groups
#define PER_CH_B (4 * 128 + 508 * 2)      // 1528
#define N_B (PER_CH_B * NCH)              // 36,672
#define N_TOTAL (N_INT + N_B)             // 804,768

__global__ __launch_bounds__(256, 4) void aa_kernel(const float* __restrict__ in,
                                                    float* __restrict__ out) {
    const int gid = blockIdx.x * 256 + threadIdx.x;

    if (gid < N_INT) {
        // ---------------- interior: 2x4 tile, scalar fp32 ----------------
        const int ch  = gid / PER_CH_T;
        const int rem = gid - ch * PER_CH_T;
        const int ty  = rem / XG_INT;
        const int y0  = 2 + ty * 2;                       // top output row
        const int x0  = 4 + (rem - ty * XG_INT) * 4;

        const float* __restrict__ img = in + ch * (IMG_H * IMG_W);
        const float* base = img + (y0 - 2) * IMG_W + (x0 - 2);

        // 6x8 window as float2[6][4]; v(r,c) helper below
        float2 L[6][4];
        #pragma unroll
        for (int r = 0; r < 6; ++r) {
            const float2* rp = (const float2*)(base + r * IMG_W);
            #pragma unroll
            for (int c = 0; c < 4; ++c) L[r][c] = rp[c];
        }
        #define V(r, c) (((c) & 1) ? L[r][(c) >> 1].y : L[r][(c) >> 1].x)

        // --- separable gaussian: column pass (unnormalized k1), row pass (k1/SSUM) ---
        float cs[2][8];
        #pragma unroll
        for (int yr = 0; yr < 2; ++yr) {
            #pragma unroll
            for (int c = 0; c < 8; ++c) {
                float s = k1(2) * V(yr + 0, c);
                s = fmaf(k1(1), V(yr + 1, c), s);
                s = fmaf(k1(0), V(yr + 2, c), s);
                s = fmaf(k1(1), V(yr + 3, c), s);
                s = fmaf(k1(2), V(yr + 4, c), s);
                cs[yr][c] = s;
            }
        }

        float res[2][4];
        #pragma unroll
        for (int yr = 0; yr < 2; ++yr) {
            #pragma unroll
            for (int p = 0; p < 4; ++p) {
                const float ctr = V(2 + yr, 2 + p);
                float wsum = 0.f, bsum = 0.f;
                #pragma unroll
                for (int i = 0; i < 5; ++i) {
                    #pragma unroll
                    for (int j = 0; j < 5; ++j) {
                        const int r2 = (i - 2) * (i - 2) + (j - 2) * (j - 2);
                        const float lsw = LG * (float)r2;
                        const float val = V(yr + i, p + j);
                        const float d   = val - ctr;
                        const float t   = d * d;
                        const float w   = fexp2(fmaf(t, NEG50, lsw));
                        wsum += w;
                        bsum = fmaf(w, val, bsum);
                    }
                }
                // gaussian from column sums (row pass, normalized taps)
                float g = k1n(2) * cs[yr][p];
                g = fmaf(k1n(1), cs[yr][p + 1], g);
                g = fmaf(k1n(0), cs[yr][p + 2], g);
                g = fmaf(k1n(1), cs[yr][p + 3], g);
                g = fmaf(k1n(2), cs[yr][p + 4], g);

                res[yr][p] = fmaf(0.6f, g, 0.4f * (bsum * frcp(wsum + 1e-8f)));
            }
        }
        #undef V

        float* op = out + ch * (IMG_H * IMG_W) + y0 * IMG_W + x0;
        *(float4*)op            = make_float4(res[0][0], res[0][1], res[0][2], res[0][3]);
        *(float4*)(op + IMG_W)  = make_float4(res[1][0], res[1][1], res[1][2], res[1][3]);
    } else {
        // ------------- border: reflect (bilateral) + zero-pad (gaussian) -------------
        const int bi = gid - N_INT;
        if (bi >= N_B) return;                    // grid pad guard (96 threads)
        const int ch = bi / PER_CH_B;
        const int r  = bi - ch * PER_CH_B;
        int y, x0;
        if (r < 512) {
            const int q = r >> 7;                 // 0..3 -> rows {0,1,510,511}
            y  = (q < 2) ? q : q + 508;
            x0 = (r & 127) << 2;
        } else {
            const int r2_ = r - 512;
            y  = 2 + (r2_ >> 1);
            x0 = (r2_ & 1) ? (IMG_W - 4) : 0;
        }

        const float* __restrict__ img = in + ch * (IMG_H * IMG_W);

        float res[4];
        #pragma unroll
        for (int p = 0; p < 4; ++p) {
            const int x = x0 + p;
            const float ctr = img[y * IMG_W + x];
            float g = 0.f, wsum = 0.f, bsum = 0.f;
            #pragma unroll
            for (int i = 0; i < 5; ++i) {
                const int yy = y + i - 2;
                const bool yin = (yy >= 0) & (yy < IMG_H);
                const int ry = (yy < 0) ? -yy : ((yy >= IMG_H) ? 2 * IMG_H - 2 - yy : yy);
                #pragma unroll
                for (int j = 0; j < 5; ++j) {
                    const int r2 = (i - 2) * (i - 2) + (j - 2) * (j - 2);
                    const float gk  = gkc(r2);
                    const float lsw = LG * (float)r2;
                    const int xx = x + j - 2;
                    const bool xin = (xx >= 0) & (xx < IMG_W);
                    const int rx = (xx < 0) ? -xx : ((xx >= IMG_W) ? 2 * IMG_W - 2 - xx : xx);
                    const float val = img[ry * IMG_W + rx];
                    const float d   = val - ctr;
                    const float w   = fexp2(fmaf(d * d, NEG50, lsw));
                    wsum += w;
                    bsum = fmaf(w, val, bsum);
                    if (yin & xin) g = fmaf(gk, val, g);
                }
            }
            res[p] = fmaf(0.6f, g, 0.4f * (bsum * frcp(wsum + 1e-8f)));
        }

        float4* o4 = (float4*)(out + ch * (IMG_H * IMG_W) + y * IMG_W + x0);
        *o4 = make_float4(res[0], res[1], res[2], res[3]);
    }
}

extern "C" void kernel_launch(void* const* d_in, const int* in_sizes, int n_in,
                              void* d_out, int out_size, void* d_ws, size_t ws_size,
                              hipStream_t stream) {
    const float* img = (const float*)d_in[0];
    float* out = (float*)d_out;
    const int blocks = (N_TOTAL + 255) / 256;     // 3144
    aa_kernel<<<blocks, 256, 0, stream>>>(img, out);
}

// Round 6
// 40.289 us; speedup vs baseline: 1.0116x; 1.0116x over previous
//
#include <hip/hip_runtime.h>

#define IMG_H 512
#define IMG_W 512
#define NCH   24   // 8 batches * 3 channels

__device__ __forceinline__ float fexp2(float x) {
#if __has_builtin(__builtin_amdgcn_exp2f)
    return __builtin_amdgcn_exp2f(x);
#else
    float r; asm("v_exp_f32 %0, %1" : "=v"(r) : "v"(x)); return r;
#endif
}
__device__ __forceinline__ float frcp(float x) {
#if __has_builtin(__builtin_amdgcn_rcpf)
    return __builtin_amdgcn_rcpf(x);
#else
    float r; asm("v_rcp_f32 %0, %1" : "=v"(r) : "v"(x)); return r;
#endif
}

// exp(-r2/2) (double, folded at compile time)
__device__ __forceinline__ constexpr double exs(int r2) {
    return (r2 == 0) ? 1.0
         : (r2 == 1) ? 0.60653065971263342
         : (r2 == 2) ? 0.36787944117144233
         : (r2 == 4) ? 0.13533528323661270
         : (r2 == 5) ? 0.08208499862389880
         : (r2 == 8) ? 0.01831563888873418 : 0.0;
}
#define SSUM 6.16892408102888092
__device__ __forceinline__ constexpr float gkc(int r2) { return (float)(exs(r2) / SSUM); }
__device__ __forceinline__ constexpr float k1(int d)  { return (float)exs(d * d); }
__device__ __forceinline__ constexpr float k1n(int d) { return (float)(exs(d * d) / SSUM); }
// -50/ln2 (intensity) and -0.5/ln2 (spatial, per unit r2), log2 domain
#define NEG50  -72.134752044448169f
#define LG     -0.72134752044448169f

// Interior: 2x4-pixel tiles. x0 in {4..504} (126 groups), row-pairs y0 in {2,4,..,508} (254)
#define XG_INT 126
#define YT_INT 254
#define PER_CH_T (XG_INT * YT_INT)        // 32004 tiles/channel
#define N_INT (PER_CH_T * NCH)            // 768,096 threads
#define PER_CH_B (4 * 128 + 508 * 2)      // 1528
#define N_B (PER_CH_B * NCH)              // 36,672
#define N_TOTAL (N_INT + N_B)             // 804,768

__global__ __launch_bounds__(256, 2) void aa_kernel(const float* __restrict__ in,
                                                    float* __restrict__ out) {
    const int gid = blockIdx.x * 256 + threadIdx.x;

    if (gid < N_INT) {
        // ---------------- interior: 2x4 tile, batched-exp fast path ----------------
        const int ch  = gid / PER_CH_T;
        const int rem = gid - ch * PER_CH_T;
        const int ty  = rem / XG_INT;
        const int y0  = 2 + ty * 2;                       // top output row
        const int x0  = 4 + (rem - ty * XG_INT) * 4;

        const float* __restrict__ img = in + ch * (IMG_H * IMG_W);
        const float* base = img + (y0 - 2) * IMG_W + (x0 - 2);

        // 6x8 window as float2[6][4]
        float2 L[6][4];
        #pragma unroll
        for (int r = 0; r < 6; ++r) {
            const float2* rp = (const float2*)(base + r * IMG_W);
            #pragma unroll
            for (int c = 0; c < 4; ++c) L[r][c] = rp[c];
        }
        #define V(r, c) (((c) & 1) ? L[r][(c) >> 1].y : L[r][(c) >> 1].x)

        // separable gaussian: column pass (unnormalized), row pass (normalized)
        float cs[2][8];
        #pragma unroll
        for (int yr = 0; yr < 2; ++yr) {
            #pragma unroll
            for (int c = 0; c < 8; ++c) {
                float s = k1(2) * V(yr + 0, c);
                s = fmaf(k1(1), V(yr + 1, c), s);
                s = fmaf(k1(0), V(yr + 2, c), s);
                s = fmaf(k1(1), V(yr + 3, c), s);
                s = fmaf(k1(2), V(yr + 4, c), s);
                cs[yr][c] = s;
            }
        }

        float res[2][4];
        #pragma unroll
        for (int yr = 0; yr < 2; ++yr) {
            #pragma unroll
            for (int p = 0; p < 4; ++p) {
                const float ctr = V(2 + yr, 2 + p);

                // phase 1: all 24 exponent args into registers
                float arg[24];
                {
                    int t = 0;
                    #pragma unroll
                    for (int i = 0; i < 5; ++i) {
                        #pragma unroll
                        for (int j = 0; j < 5; ++j) {
                            if (i == 2 && j == 2) continue;   // center: w == 1 exactly
                            const int r2 = (i - 2) * (i - 2) + (j - 2) * (j - 2);
                            const float val = V(yr + i, p + j);
                            const float d   = val - ctr;
                            arg[t] = fmaf(d * d, NEG50, LG * (float)r2);
                            ++t;
                        }
                    }
                }
                // phase 2: 24 independent v_exp_f32 back-to-back
                float w[24];
                #pragma unroll
                for (int k = 0; k < 24; ++k) w[k] = fexp2(arg[k]);

                // phase 3: reduce
                float wsum = 1.0f, bsum = ctr;                // center tap folded in
                {
                    int t = 0;
                    #pragma unroll
                    for (int i = 0; i < 5; ++i) {
                        #pragma unroll
                        for (int j = 0; j < 5; ++j) {
                            if (i == 2 && j == 2) continue;
                            const float val = V(yr + i, p + j);
                            wsum += w[t];
                            bsum = fmaf(w[t], val, bsum);
                            ++t;
                        }
                    }
                }

                // gaussian from column sums (row pass, normalized taps)
                float g = k1n(2) * cs[yr][p];
                g = fmaf(k1n(1), cs[yr][p + 1], g);
                g = fmaf(k1n(0), cs[yr][p + 2], g);
                g = fmaf(k1n(1), cs[yr][p + 3], g);
                g = fmaf(k1n(2), cs[yr][p + 4], g);

                res[yr][p] = fmaf(0.6f, g, 0.4f * (bsum * frcp(wsum + 1e-8f)));
            }
        }
        #undef V

        float* op = out + ch * (IMG_H * IMG_W) + y0 * IMG_W + x0;
        *(float4*)op            = make_float4(res[0][0], res[0][1], res[0][2], res[0][3]);
        *(float4*)(op + IMG_W)  = make_float4(res[1][0], res[1][1], res[1][2], res[1][3]);
    } else {
        // ------------- border: reflect (bilateral) + zero-pad (gaussian) -------------
        const int bi = gid - N_INT;
        if (bi >= N_B) return;
        const int ch = bi / PER_CH_B;
        const int r  = bi - ch * PER_CH_B;
        int y, x0;
        if (r < 512) {
            const int q = r >> 7;                 // 0..3 -> rows {0,1,510,511}
            y  = (q < 2) ? q : q + 508;
            x0 = (r & 127) << 2;
        } else {
            const int r2_ = r - 512;
            y  = 2 + (r2_ >> 1);
            x0 = (r2_ & 1) ? (IMG_W - 4) : 0;
        }

        const float* __restrict__ img = in + ch * (IMG_H * IMG_W);

        float res[4];
        #pragma unroll
        for (int p = 0; p < 4; ++p) {
            const int x = x0 + p;
            const float ctr = img[y * IMG_W + x];
            float g = 0.f, wsum = 1.0f, bsum = ctr;           // center folded in
            #pragma unroll
            for (int i = 0; i < 5; ++i) {
                const int yy = y + i - 2;
                const bool yin = (yy >= 0) & (yy < IMG_H);
                const int ry = (yy < 0) ? -yy : ((yy >= IMG_H) ? 2 * IMG_H - 2 - yy : yy);
                #pragma unroll
                for (int j = 0; j < 5; ++j) {
                    const int r2 = (i - 2) * (i - 2) + (j - 2) * (j - 2);
                    const float gk  = gkc(r2);
                    const float lsw = LG * (float)r2;
                    const int xx = x + j - 2;
                    const bool xin = (xx >= 0) & (xx < IMG_W);
                    const int rx = (xx < 0) ? -xx : ((xx >= IMG_W) ? 2 * IMG_W - 2 - xx : xx);
                    const float val = img[ry * IMG_W + rx];
                    if (i == 2 && j == 2) {
                        if (yin & xin) g = fmaf(gk, val, g);  // weights already folded
                        continue;
                    }
                    const float d   = val - ctr;
                    const float w   = fexp2(fmaf(d * d, NEG50, lsw));
                    wsum += w;
                    bsum = fmaf(w, val, bsum);
                    if (yin & xin) g = fmaf(gk, val, g);
                }
            }
            res[p] = fmaf(0.6f, g, 0.4f * (bsum * frcp(wsum + 1e-8f)));
        }

        float4* o4 = (float4*)(out + ch * (IMG_H * IMG_W) + y * IMG_W + x0);
        *o4 = make_float4(res[0], res[1], res[2], res[3]);
    }
}

extern "C" void kernel_launch(void* const* d_in, const int* in_sizes, int n_in,
                              void* d_out, int out_size, void* d_ws, size_t ws_size,
                              hipStream_t stream) {
    const float* img = (const float*)d_in[0];
    float* out = (float*)d_out;
    const int blocks = (N_TOTAL + 255) / 256;     // 3144
    aa_kernel<<<blocks, 256, 0, stream>>>(img, out);
}

// Round 7
// 37.376 us; speedup vs baseline: 1.0904x; 1.0780x over previous
//
#include <hip/hip_runtime.h>

#define IMG_H 512
#define IMG_W 512
#define HW    (IMG_H * IMG_W)
#define NCH   24   // 8 batches * 3 channels

__device__ __forceinline__ float fexp2(float x) {
#if __has_builtin(__builtin_amdgcn_exp2f)
    return __builtin_amdgcn_exp2f(x);
#else
    float r; asm("v_exp_f32 %0, %1" : "=v"(r) : "v"(x)); return r;
#endif
}
__device__ __forceinline__ float frcp(float x) {
#if __has_builtin(__builtin_amdgcn_rcpf)
    return __builtin_amdgcn_rcpf(x);
#else
    float r; asm("v_rcp_f32 %0, %1" : "=v"(r) : "v"(x)); return r;
#endif
}

// exp(-r2/2) (double, folded at compile time)
__device__ __forceinline__ constexpr double exs(int r2) {
    return (r2 == 0) ? 1.0
         : (r2 == 1) ? 0.60653065971263342
         : (r2 == 2) ? 0.36787944117144233
         : (r2 == 4) ? 0.13533528323661270
         : (r2 == 5) ? 0.08208499862389880
         : (r2 == 8) ? 0.01831563888873418 : 0.0;
}
#define SSUM 6.16892408102888092
__device__ __forceinline__ constexpr float k1(int d)  { return (float)exs(d * d); }
__device__ __forceinline__ constexpr float k1n(int d) { return (float)(exs(d * d) / SSUM); }
// -50/ln2 (intensity) and -0.5/ln2 (spatial, per unit r2), log2 domain
#define NEG50  -72.134752044448169f
#define LG     -0.72134752044448169f

// Border first: 4 full rows (y=0,1,510,511)*128 groups + 508 rows * 2 edge groups
#define PER_CH_B (4 * 128 + 508 * 2)      // 1528
#define N_B (PER_CH_B * NCH)              // 36,672 = 573 waves exactly (wave-aligned)
// Interior: 2x4-pixel tiles. x0 in {4..504} (126 groups), row-pairs y0 in {2,..,508} (254)
#define XG_INT 126
#define YT_INT 254
#define PER_CH_T (XG_INT * YT_INT)        // 32004 tiles/channel
#define N_INT (PER_CH_T * NCH)            // 768,096 threads
#define N_TOTAL (N_B + N_INT)             // 804,768

__global__ __launch_bounds__(256) void aa_kernel(const float* __restrict__ in,
                                                 float* __restrict__ out) {
    const int gid = blockIdx.x * 256 + threadIdx.x;

    if (gid < N_B) {
        // ---------- border (dispatched FIRST; latency hides under interior) ----------
        const int ch = gid / PER_CH_B;
        const int r  = gid - ch * PER_CH_B;
        int y, x0;
        if (r < 512) {
            const int q = r >> 7;                 // 0..3 -> rows {0,1,510,511}
            y  = (q < 2) ? q : q + 508;
            x0 = (r & 127) << 2;
        } else {
            const int t = r - 512;
            y  = 2 + (t >> 1);
            x0 = (t & 1) ? (IMG_W - 4) : 0;
        }
        const float* __restrict__ img = in + ch * HW;

        // reflected row/col indices + gaussian zero-pad masks (separable)
        int ry[5]; float krow[5];
        #pragma unroll
        for (int i = 0; i < 5; ++i) {
            const int yy = y + i - 2;
            const int ryy = (yy < 0) ? -yy : ((yy >= IMG_H) ? 2 * IMG_H - 2 - yy : yy);
            ry[i] = ryy * IMG_W;
            krow[i] = ((yy >= 0) & (yy < IMG_H)) ? k1(i - 2) : 0.0f;
        }
        int rx[8]; float xin[8];
        #pragma unroll
        for (int c = 0; c < 8; ++c) {
            const int xx = x0 + c - 2;
            rx[c] = (xx < 0) ? -xx : ((xx >= IMG_W) ? 2 * IMG_W - 2 - xx : xx);
            xin[c] = ((xx >= 0) & (xx < IMG_W)) ? 1.0f : 0.0f;
        }
        // 5x8 window: 40 independent loads, one latency wait
        float v[5][8];
        #pragma unroll
        for (int i = 0; i < 5; ++i) {
            #pragma unroll
            for (int c = 0; c < 8; ++c) v[i][c] = img[ry[i] + rx[c]];
        }

        // gaussian column pass (row-masked, unnormalized), premasked by xin
        float csm[8];
        #pragma unroll
        for (int c = 0; c < 8; ++c) {
            float s = krow[0] * v[0][c];
            s = fmaf(krow[1], v[1][c], s);
            s = fmaf(krow[2], v[2][c], s);
            s = fmaf(krow[3], v[3][c], s);
            s = fmaf(krow[4], v[4][c], s);
            csm[c] = s * xin[c];
        }

        float res[4];
        #pragma unroll
        for (int p = 0; p < 4; ++p) {
            const float ctr = v[2][2 + p];
            float arg[24], val[24];
            {
                int t = 0;
                #pragma unroll
                for (int i = 0; i < 5; ++i) {
                    #pragma unroll
                    for (int j = 0; j < 5; ++j) {
                        if (i == 2 && j == 2) continue;   // center: w == 1
                        const int r2 = (i - 2) * (i - 2) + (j - 2) * (j - 2);
                        const float vv = v[i][p + j];
                        val[t] = vv;
                        const float d = vv - ctr;
                        arg[t] = fmaf(d * d, NEG50, LG * (float)r2);
                        ++t;
                    }
                }
            }
            float w[24];
            #pragma unroll
            for (int k = 0; k < 24; ++k) w[k] = fexp2(arg[k]);

            float ws0 = 1.0f, ws1 = 0.f, ws2 = 0.f, ws3 = 0.f;
            float bs0 = ctr,  bs1 = 0.f, bs2 = 0.f, bs3 = 0.f;
            #pragma unroll
            for (int k = 0; k < 24; k += 4) {
                ws0 += w[k];     bs0 = fmaf(w[k],     val[k],     bs0);
                ws1 += w[k + 1]; bs1 = fmaf(w[k + 1], val[k + 1], bs1);
                ws2 += w[k + 2]; bs2 = fmaf(w[k + 2], val[k + 2], bs2);
                ws3 += w[k + 3]; bs3 = fmaf(w[k + 3], val[k + 3], bs3);
            }
            const float wsum = (ws0 + ws1) + (ws2 + ws3);
            const float bsum = (bs0 + bs1) + (bs2 + bs3);

            float g = k1n(2) * csm[p];
            g = fmaf(k1n(1), csm[p + 1], g);
            g = fmaf(k1n(0), csm[p + 2], g);
            g = fmaf(k1n(1), csm[p + 3], g);
            g = fmaf(k1n(2), csm[p + 4], g);

            res[p] = fmaf(0.6f, g, 0.4f * (bsum * frcp(wsum + 1e-8f)));
        }

        float4* o4 = (float4*)(out + ch * HW + y * IMG_W + x0);
        *o4 = make_float4(res[0], res[1], res[2], res[3]);
    } else {
        // ---------------- interior: 2x4 tile, batched-exp fast path ----------------
        const int ig = gid - N_B;
        if (ig >= N_INT) return;                  // grid pad guard (96 threads)
        const int ch  = ig / PER_CH_T;
        const int rem = ig - ch * PER_CH_T;
        const int ty  = rem / XG_INT;
        const int y0  = 2 + ty * 2;               // top output row
        const int x0  = 4 + (rem - ty * XG_INT) * 4;

        const float* __restrict__ img = in + ch * HW;
        const float* base = img + (y0 - 2) * IMG_W + (x0 - 2);

        // 6x8 window as float2[6][4]
        float2 L[6][4];
        #pragma unroll
        for (int r = 0; r < 6; ++r) {
            const float2* rp = (const float2*)(base + r * IMG_W);
            #pragma unroll
            for (int c = 0; c < 4; ++c) L[r][c] = rp[c];
        }
        #define V(r, c) (((c) & 1) ? L[r][(c) >> 1].y : L[r][(c) >> 1].x)

        // separable gaussian: column pass (unnormalized), row pass (normalized)
        float cs[2][8];
        #pragma unroll
        for (int yr = 0; yr < 2; ++yr) {
            #pragma unroll
            for (int c = 0; c < 8; ++c) {
                float s = k1(2) * V(yr + 0, c);
                s = fmaf(k1(1), V(yr + 1, c), s);
                s = fmaf(k1(0), V(yr + 2, c), s);
                s = fmaf(k1(1), V(yr + 3, c), s);
                s = fmaf(k1(2), V(yr + 4, c), s);
                cs[yr][c] = s;
            }
        }

        float res[2][4];
        #pragma unroll
        for (int yr = 0; yr < 2; ++yr) {
            #pragma unroll
            for (int p = 0; p < 4; ++p) {
                const float ctr = V(2 + yr, 2 + p);

                float arg[24], val[24];
                {
                    int t = 0;
                    #pragma unroll
                    for (int i = 0; i < 5; ++i) {
                        #pragma unroll
                        for (int j = 0; j < 5; ++j) {
                            if (i == 2 && j == 2) continue;   // center: w == 1
                            const int r2 = (i - 2) * (i - 2) + (j - 2) * (j - 2);
                            const float vv = V(yr + i, p + j);
                            val[t] = vv;
                            const float d = vv - ctr;
                            arg[t] = fmaf(d * d, NEG50, LG * (float)r2);
                            ++t;
                        }
                    }
                }
                float w[24];
                #pragma unroll
                for (int k = 0; k < 24; ++k) w[k] = fexp2(arg[k]);

                float ws0 = 1.0f, ws1 = 0.f, ws2 = 0.f, ws3 = 0.f;
                float bs0 = ctr,  bs1 = 0.f, bs2 = 0.f, bs3 = 0.f;
                #pragma unroll
                for (int k = 0; k < 24; k += 4) {
                    ws0 += w[k];     bs0 = fmaf(w[k],     val[k],     bs0);
                    ws1 += w[k + 1]; bs1 = fmaf(w[k + 1], val[k + 1], bs1);
                    ws2 += w[k + 2]; bs2 = fmaf(w[k + 2], val[k + 2], bs2);
                    ws3 += w[k + 3]; bs3 = fmaf(w[k + 3], val[k + 3], bs3);
                }
                const float wsum = (ws0 + ws1) + (ws2 + ws3);
                const float bsum = (bs0 + bs1) + (bs2 + bs3);

                float g = k1n(2) * cs[yr][p];
                g = fmaf(k1n(1), cs[yr][p + 1], g);
                g = fmaf(k1n(0), cs[yr][p + 2], g);
                g = fmaf(k1n(1), cs[yr][p + 3], g);
                g = fmaf(k1n(2), cs[yr][p + 4], g);

                res[yr][p] = fmaf(0.6f, g, 0.4f * (bsum * frcp(wsum + 1e-8f)));
            }
        }
        #undef V

        float* op = out + ch * HW + y0 * IMG_W + x0;
        *(float4*)op           = make_float4(res[0][0], res[0][1], res[0][2], res[0][3]);
        *(float4*)(op + IMG_W) = make_float4(res[1][0], res[1][1], res[1][2], res[1][3]);
    }
}

extern "C" void kernel_launch(void* const* d_in, const int* in_sizes, int n_in,
                              void* d_out, int out_size, void* d_ws, size_t ws_size,
                              hipStream_t stream) {
    const float* img = (const float*)d_in[0];
    float* out = (float*)d_out;
    const int blocks = (N_TOTAL + 255) / 256;     // 3144
    aa_kernel<<<blocks, 256, 0, stream>>>(img, out);
}